// Round 7
// baseline (527.965 us; speedup 1.0000x reference)
//
#include <hip/hip_runtime.h>
#include <hip/hip_bf16.h>
#include <math.h>

#define EPSQ 1e-5f

typedef __attribute__((ext_vector_type(4))) int i32x4;

__device__ __forceinline__ void gload_lds16(const void* g, void* l) {
  __builtin_amdgcn_global_load_lds(
      (__attribute__((address_space(1))) void*)g,
      (__attribute__((address_space(3))) void*)l, 16, 0, 0);
}

__device__ __forceinline__ int clampi8(float v, float lo, float hi) {
  return (int)rintf(fminf(hi, fmaxf(lo, v)));
}

// ---------------- fused weight |w| sums: one dispatch, 3 weights ----------------
__global__ void wabs3_kernel(const float* __restrict__ w1, const float* __restrict__ w2,
                             const float* __restrict__ w3, int n4,
                             double* __restrict__ sums) {
  const float* w = (blockIdx.y == 0) ? w1 : (blockIdx.y == 1) ? w2 : w3;
  __shared__ double sm[256];
  const float4* w4 = (const float4*)w;
  double acc = 0.0;
  const int stride = gridDim.x * blockDim.x;
  for (int i = blockIdx.x * blockDim.x + threadIdx.x; i < n4; i += stride) {
    float4 v = w4[i];
    acc += (double)fabsf(v.x) + (double)fabsf(v.y) + (double)fabsf(v.z) + (double)fabsf(v.w);
  }
  sm[threadIdx.x] = acc;
  __syncthreads();
  for (int s = 128; s > 0; s >>= 1) {
    if ((int)threadIdx.x < s) sm[threadIdx.x] += sm[threadIdx.x + s];
    __syncthreads();
  }
  if (threadIdx.x == 0) atomicAdd(sums + blockIdx.y, sm[0]);
}

// ---------------- fused ternary weight quant: one dispatch, 3 weights ----------------
__global__ void wquant3_kernel(const float* __restrict__ w1, const float* __restrict__ w2,
                               const float* __restrict__ w3, int n4,
                               const double* __restrict__ sums, double inv_n,
                               unsigned int* __restrict__ q1, unsigned int* __restrict__ q2,
                               unsigned int* __restrict__ q3) {
  const int wsel = blockIdx.y;
  const float* w = (wsel == 0) ? w1 : (wsel == 1) ? w2 : w3;
  unsigned int* wq = (wsel == 0) ? q1 : (wsel == 1) ? q2 : q3;
  const float s = (float)fmax(sums[wsel] * inv_n, (double)EPSQ);
  const float scale = 1.0f / s;  // same fp32 division as the reference
  const int i = blockIdx.x * blockDim.x + threadIdx.x;
  if (i >= n4) return;
  float4 v = ((const float4*)w)[i];
  const int b0 = clampi8(rintf(v.x * scale), -1.f, 1.f);
  const int b1 = clampi8(rintf(v.y * scale), -1.f, 1.f);
  const int b2 = clampi8(rintf(v.z * scale), -1.f, 1.f);
  const int b3 = clampi8(rintf(v.w * scale), -1.f, 1.f);
  wq[i] = (unsigned int)((b0 & 0xff) | ((b1 & 0xff) << 8) |
                         ((b2 & 0xff) << 16) | ((b3 & 0xff) << 24));
}

// ---------------- per-token absmax int8 quant (2-pass, for x) ----------------
__global__ void aquant_kernel(const float* __restrict__ x, int K,
                              unsigned char* __restrict__ q, float* __restrict__ arow) {
  const int row = blockIdx.x;
  const int n4 = K >> 2;
  const float4* xr = (const float4*)(x + (size_t)row * K);
  float m = 0.f;
  for (int c = threadIdx.x; c < n4; c += blockDim.x) {
    float4 v = xr[c];
    m = fmaxf(m, fmaxf(fmaxf(fabsf(v.x), fabsf(v.y)), fmaxf(fabsf(v.z), fabsf(v.w))));
  }
  __shared__ float sm[256];
  sm[threadIdx.x] = m;
  __syncthreads();
  for (int s = 128; s > 0; s >>= 1) {
    if ((int)threadIdx.x < s) sm[threadIdx.x] = fmaxf(sm[threadIdx.x], sm[threadIdx.x + s]);
    __syncthreads();
  }
  const float mv = fmaxf(sm[0], EPSQ);
  const float scale = 127.0f / mv;   // same fp32 division as the reference
  if (threadIdx.x == 0) arow[row] = mv * (1.0f / 127.0f);
  unsigned int* qr = (unsigned int*)(q + (size_t)row * K);
  for (int c = threadIdx.x; c < n4; c += blockDim.x) {
    float4 v = xr[c];
    const int b0 = clampi8(v.x * scale, -128.f, 127.f);
    const int b1 = clampi8(v.y * scale, -128.f, 127.f);
    const int b2 = clampi8(v.z * scale, -128.f, 127.f);
    const int b3 = clampi8(v.w * scale, -128.f, 127.f);
    qr[c] = (unsigned int)((b0 & 0xff) | ((b1 & 0xff) << 8) |
                           ((b2 & 0xff) << 16) | ((b3 & 0xff) << 24));
  }
}

// ---------------- single-pass quant for h: reduce per-block partial maxima ----------------
__global__ void aquant_pre_kernel(const float* __restrict__ x, int K,
                                  const float* __restrict__ hpart, int nslice,
                                  unsigned char* __restrict__ q, float* __restrict__ arow) {
  const int row = blockIdx.x;
  __shared__ float sm[256];
  float m = 0.f;
  for (int t = threadIdx.x; t < nslice; t += blockDim.x)
    m = fmaxf(m, hpart[(size_t)row * nslice + t]);
  sm[threadIdx.x] = m;
  __syncthreads();
  for (int s = 128; s > 0; s >>= 1) {
    if ((int)threadIdx.x < s) sm[threadIdx.x] = fmaxf(sm[threadIdx.x], sm[threadIdx.x + s]);
    __syncthreads();
  }
  const float mv = fmaxf(sm[0], EPSQ);
  const float scale = 127.0f / mv;
  if (threadIdx.x == 0) arow[row] = mv * (1.0f / 127.0f);
  const int n4 = K >> 2;
  const float4* xr = (const float4*)(x + (size_t)row * K);
  unsigned int* qr = (unsigned int*)(q + (size_t)row * K);
  for (int c = threadIdx.x; c < n4; c += blockDim.x) {
    float4 v = xr[c];
    const int b0 = clampi8(v.x * scale, -128.f, 127.f);
    const int b1 = clampi8(v.y * scale, -128.f, 127.f);
    const int b2 = clampi8(v.z * scale, -128.f, 127.f);
    const int b3 = clampi8(v.w * scale, -128.f, 127.f);
    qr[c] = (unsigned int)((b0 & 0xff) | ((b1 & 0xff) << 8) |
                           ((b2 & 0xff) << 16) | ((b3 & 0xff) << 24));
  }
}

// =================================================================================
// Pipelined i8 GEMMs: tile 128(M)x128(N), BK=64, 8 waves (2Mx4N, 64x32 each),
// triple-buffered LDS (72KB gateup / 48KB down -> 2 blocks/CU), counted vmcnt,
// raw s_barrier, XOR-swizzled LDS (pre-swizzled global src + swizzled ds_read).
// =================================================================================
#define BKP 64

#define PIPE_BARRIER(N)                                         \
  asm volatile("s_waitcnt vmcnt(" #N ")" ::: "memory");         \
  __builtin_amdgcn_s_barrier();                                 \
  asm volatile("" ::: "memory");

// ---------------- fused gate/up GEMM (int8, pipelined) ----------------
#define GU_SLOT 24576   // A 8KB + B1 8KB + B2 8KB

__launch_bounds__(512, 2)
__global__ void gemm_gateup(const unsigned char* __restrict__ Aq,   // [Mc][K] i8
                            const unsigned char* __restrict__ W1q,  // [N][K] i8 ternary
                            const unsigned char* __restrict__ W2q,  // [N][K]
                            const float* __restrict__ arow,         // [Mc] = rowmax/127
                            const double* __restrict__ wsum,
                            float* __restrict__ Hbuf,               // [Mc][N] fp32
                            float* __restrict__ hpart,              // [Mc][4*NBb] partial |h| max
                            const int N, const int K,
                            const int MBb, const int NBb) {
  __shared__ char lds[3 * GU_SLOT];   // 72 KiB -> 2 blocks/CU

  const int tid = threadIdx.x;
  const int lane = tid & 63;
  const int wid = tid >> 6;          // 8 waves
  const int wm = wid >> 2;           // 0..1 (M)
  const int wn = wid & 3;            // 0..3 (N)

  // T1: XCD-aware block swizzle (bijective when total % 8 == 0)
  const int total = MBb * NBb;
  int swz = blockIdx.x;
  if ((total & 7) == 0) swz = (swz & 7) * (total >> 3) + (swz >> 3);
  const int nb = swz % NBb;          // nb fast: neighbors share the A panel
  const int mb = swz / NBb;
  const int m0 = mb * 128;
  const int n0 = nb * 128;

  const unsigned char* Ab  = Aq  + (size_t)m0 * K;
  const unsigned char* B1b = W1q + (size_t)n0 * K;
  const unsigned char* B2b = W2q + (size_t)n0 * K;

  // stage one K-tile into slot s: 3 issues per wave (A,B1,B2) -> 3 per tile in vmcnt
  auto stage = [&](int kt, int s) {
    const int k0 = kt * BKP;
    char* base = lds + s * GU_SLOT;
    const int p = wid * 1024 + lane * 16;     // phys byte in 8KB region
    const int r = p >> 6;
    const int c = ((p >> 4) & 3) ^ ((r >> 1) & 3);   // inverse-swizzled source
    const size_t go = (size_t)r * K + k0 + c * 16;
    gload_lds16(Ab  + go, base + wid * 1024);
    gload_lds16(B1b + go, base + 8192 + wid * 1024);
    gload_lds16(B2b + go, base + 16384 + wid * 1024);
  };

  // precomputed swizzled read offsets (K-invariant)
  const int c16 = lane >> 4;
  int offA[4], offB1[2], offB2[2];
#pragma unroll
  for (int i = 0; i < 4; ++i) {
    const int row = wm * 64 + i * 16 + (lane & 15);
    offA[i] = row * 64 + ((c16 ^ ((row >> 1) & 3)) << 4);
  }
#pragma unroll
  for (int j = 0; j < 2; ++j) {
    const int n = wn * 32 + j * 16 + (lane & 15);
    const int o = n * 64 + ((c16 ^ ((n >> 1) & 3)) << 4);
    offB1[j] = 8192 + o;
    offB2[j] = 16384 + o;
  }

  i32x4 acc1[4][2] = {};
  i32x4 acc2[4][2] = {};

  const int NT = K / BKP;
  stage(0, 0);
  stage(1, 1);
  PIPE_BARRIER(3)                    // tile 0 landed; tile 1 (3 issues) in flight

  int s = 0, s2 = 2;
  for (int t = 0; t < NT; ++t) {
    if (t + 2 < NT) stage(t + 2, s2);   // issue-early; slot of t-1 (read-complete)
    const char* sb = lds + s * GU_SLOT;
    i32x4 af[4], b1f[2], b2f[2];
#pragma unroll
    for (int i = 0; i < 4; ++i) af[i] = *(const i32x4*)(sb + offA[i]);
#pragma unroll
    for (int j = 0; j < 2; ++j) {
      b1f[j] = *(const i32x4*)(sb + offB1[j]);
      b2f[j] = *(const i32x4*)(sb + offB2[j]);
    }
    __builtin_amdgcn_s_setprio(1);
#pragma unroll
    for (int j = 0; j < 2; ++j)
#pragma unroll
      for (int i = 0; i < 4; ++i) {
        acc1[i][j] = __builtin_amdgcn_mfma_i32_16x16x64_i8(af[i], b1f[j], acc1[i][j], 0, 0, 0);
        acc2[i][j] = __builtin_amdgcn_mfma_i32_16x16x64_i8(af[i], b2f[j], acc2[i][j], 0, 0, 0);
      }
    __builtin_amdgcn_s_setprio(0);
    if (t + 2 < NT) {
      PIPE_BARRIER(3)                // t+1 landed; t+2 stays in flight
    } else if (t + 1 < NT) {
      PIPE_BARRIER(0)                // tail: drain last tile
    }
    s = (s == 2) ? 0 : s + 1;
    s2 = (s2 == 2) ? 0 : s2 + 1;
  }

  // epilogue: dequant + silu(gate)*up, write fp32 H + per-(block,wn) row |h| max
  const double inv_n = 1.0 / 11534336.0;
  const float sw1 = (float)fmax(wsum[0] * inv_n, (double)EPSQ);
  const float sw2 = (float)fmax(wsum[1] * inv_n, (double)EPSQ);
  const int nslice = NBb * 4;
  const int slice = nb * 4 + wn;
#pragma unroll
  for (int i = 0; i < 4; ++i) {
    const int rb = m0 + wm * 64 + i * 16 + (lane >> 4) * 4;
#pragma unroll
    for (int qe = 0; qe < 4; ++qe) {
      const int grow = rb + qe;
      const float a = arow[grow];
      const float f1 = a * sw1;
      const float f2 = a * sw2;
      float* hr = Hbuf + (size_t)grow * N + n0 + wn * 32 + (lane & 15);
      float lmax = 0.f;
#pragma unroll
      for (int j = 0; j < 2; ++j) {
        const float y1 = (float)acc1[i][j][qe] * f1;
        const float y2 = (float)acc2[i][j][qe] * f2;
        const float h = (y1 / (1.0f + expf(-y1))) * y2;   // silu(y1)*y2
        hr[j * 16] = h;
        lmax = fmaxf(lmax, fabsf(h));
      }
      // reduce across the 16 lanes sharing this row (same lane>>4)
#pragma unroll
      for (int mk = 8; mk >= 1; mk >>= 1)
        lmax = fmaxf(lmax, __shfl_xor(lmax, mk, 64));
      if ((lane & 15) == 0)
        hpart[(size_t)grow * nslice + slice] = lmax;   // plain store, no atomics
    }
  }
}

// ---------------- down GEMM (int8, pipelined): Out = Q2 * W3^T ----------------
#define DN_SLOT 16384   // A 8KB + B 8KB

__launch_bounds__(512, 2)
__global__ void gemm_down(const unsigned char* __restrict__ Aq,   // [Mc][K] i8
                          const unsigned char* __restrict__ Wq,   // [N][K] i8 ternary
                          const float* __restrict__ arow,
                          const double* __restrict__ wsum,
                          float* __restrict__ Out,                // [Mc][N] fp32
                          const int N, const int K,
                          const int MBb, const int NBb) {
  __shared__ char lds[3 * DN_SLOT];   // 48 KiB -> 2-3 blocks/CU

  const int tid = threadIdx.x;
  const int lane = tid & 63;
  const int wid = tid >> 6;
  const int wm = wid >> 2;
  const int wn = wid & 3;

  const int total = MBb * NBb;
  int swz = blockIdx.x;
  if ((total & 7) == 0) swz = (swz & 7) * (total >> 3) + (swz >> 3);
  const int nb = swz % NBb;
  const int mb = swz / NBb;
  const int m0 = mb * 128;
  const int n0 = nb * 128;

  const unsigned char* Ab = Aq + (size_t)m0 * K;
  const unsigned char* Bb = Wq + (size_t)n0 * K;

  auto stage = [&](int kt, int s) {
    const int k0 = kt * BKP;
    char* base = lds + s * DN_SLOT;
    const int p = wid * 1024 + lane * 16;
    const int r = p >> 6;
    const int c = ((p >> 4) & 3) ^ ((r >> 1) & 3);
    const size_t go = (size_t)r * K + k0 + c * 16;
    gload_lds16(Ab + go, base + wid * 1024);
    gload_lds16(Bb + go, base + 8192 + wid * 1024);
  };

  const int c16 = lane >> 4;
  int offA[4], offB[2];
#pragma unroll
  for (int i = 0; i < 4; ++i) {
    const int row = wm * 64 + i * 16 + (lane & 15);
    offA[i] = row * 64 + ((c16 ^ ((row >> 1) & 3)) << 4);
  }
#pragma unroll
  for (int j = 0; j < 2; ++j) {
    const int n = wn * 32 + j * 16 + (lane & 15);
    offB[j] = 8192 + n * 64 + ((c16 ^ ((n >> 1) & 3)) << 4);
  }

  i32x4 acc[4][2] = {};

  const int NT = K / BKP;
  stage(0, 0);
  stage(1, 1);
  PIPE_BARRIER(2)                    // 4 issued; tile 0 (2) landed

  int s = 0, s2 = 2;
  for (int t = 0; t < NT; ++t) {
    if (t + 2 < NT) stage(t + 2, s2);
    const char* sb = lds + s * DN_SLOT;
    i32x4 af[4], bf[2];
#pragma unroll
    for (int i = 0; i < 4; ++i) af[i] = *(const i32x4*)(sb + offA[i]);
#pragma unroll
    for (int j = 0; j < 2; ++j) bf[j] = *(const i32x4*)(sb + offB[j]);
    __builtin_amdgcn_s_setprio(1);
#pragma unroll
    for (int j = 0; j < 2; ++j)
#pragma unroll
      for (int i = 0; i < 4; ++i)
        acc[i][j] = __builtin_amdgcn_mfma_i32_16x16x64_i8(af[i], bf[j], acc[i][j], 0, 0, 0);
    __builtin_amdgcn_s_setprio(0);
    if (t + 2 < NT) {
      PIPE_BARRIER(2)
    } else if (t + 1 < NT) {
      PIPE_BARRIER(0)
    }
    s = (s == 2) ? 0 : s + 1;
    s2 = (s2 == 2) ? 0 : s2 + 1;
  }

  const double inv_n = 1.0 / 11534336.0;
  const float sw3 = (float)fmax(wsum[2] * inv_n, (double)EPSQ);
#pragma unroll
  for (int i = 0; i < 4; ++i) {
    const int rb = m0 + wm * 64 + i * 16 + (lane >> 4) * 4;
#pragma unroll
    for (int qe = 0; qe < 4; ++qe) {
      const int grow = rb + qe;
      const float f = arow[grow] * sw3;
      float* orow = Out + (size_t)grow * N + n0 + wn * 32 + (lane & 15);
#pragma unroll
      for (int j = 0; j < 2; ++j) {
        orow[j * 16] = (float)acc[i][j][qe] * f;
      }
    }
  }
}

extern "C" void kernel_launch(void* const* d_in, const int* in_sizes, int n_in,
                              void* d_out, int out_size, void* d_ws, size_t ws_size,
                              hipStream_t stream) {
  (void)n_in; (void)out_size;
  const float* x  = (const float*)d_in[0];
  const float* w1 = (const float*)d_in[1];
  const float* w2 = (const float*)d_in[2];
  const float* w3 = (const float*)d_in[3];
  float* out = (float*)d_out;

  const int D = 2048, H = 5632;
  const int M = in_sizes[0] / D;             // 8192
  const long long NW = (long long)H * D;     // 11534336
  const int NBgu = H / 128;                  // 44
  const int NBdn = D / 128;                  // 16
  const int nslice = NBgu * 4;               // 176

  auto al = [](size_t v) { return (v + 255) & ~(size_t)255; };

  // fixed region: wsum + int8 quantized weights (34.6 MB)
  size_t off = 0;
  const size_t o_wsum = off; off += al(3 * sizeof(double));
  const size_t o_w1q  = off; off += al((size_t)NW);
  const size_t o_w2q  = off; off += al((size_t)NW);
  const size_t o_w3q  = off; off += al((size_t)NW);
  const size_t fixed = off;

  // adaptive chunk size: largest Mc (multiple of 256, power-of-2 fraction of M)
  int Mc = 256;
  for (int cand = M; cand >= 256; cand >>= 1) {
    size_t need = fixed
                + al((size_t)cand * 4)            // arow1
                + al((size_t)cand * 4)            // arow2
                + al((size_t)cand * nslice * 4)   // hpart
                + al((size_t)cand * D)            // qx i8
                + al((size_t)cand * H * 4)        // hbuf fp32
                + al((size_t)cand * H);           // qh i8
    if (need <= ws_size) { Mc = cand; break; }
  }

  size_t coff = fixed;
  const size_t o_arow1 = coff; coff += al((size_t)Mc * 4);
  const size_t o_arow2 = coff; coff += al((size_t)Mc * 4);
  const size_t o_hpart = coff; coff += al((size_t)Mc * nslice * 4);
  const size_t o_qx    = coff; coff += al((size_t)Mc * D);
  const size_t o_hbuf  = coff; coff += al((size_t)Mc * H * 4);
  const size_t o_qh    = coff; coff += al((size_t)Mc * H);

  char* ws = (char*)d_ws;
  double* wsum        = (double*)(ws + o_wsum);
  unsigned char* w1q  = (unsigned char*)(ws + o_w1q);
  unsigned char* w2q  = (unsigned char*)(ws + o_w2q);
  unsigned char* w3q  = (unsigned char*)(ws + o_w3q);
  float* arow1        = (float*)(ws + o_arow1);
  float* arow2        = (float*)(ws + o_arow2);
  float* hpart        = (float*)(ws + o_hpart);
  unsigned char* qx   = (unsigned char*)(ws + o_qx);
  float* hbuf         = (float*)(ws + o_hbuf);
  unsigned char* qh   = (unsigned char*)(ws + o_qh);

  hipMemsetAsync(wsum, 0, 3 * sizeof(double), stream);

  const int n4w = (int)(NW / 4);                 // 2883584
  wabs3_kernel<<<dim3(1024, 3), 256, 0, stream>>>(w1, w2, w3, n4w, wsum);

  const double inv_n = 1.0 / (double)NW;
  wquant3_kernel<<<dim3(n4w / 256, 3), 256, 0, stream>>>(
      w1, w2, w3, n4w, wsum, inv_n,
      (unsigned int*)w1q, (unsigned int*)w2q, (unsigned int*)w3q);

  for (int c = 0; c < M; c += Mc) {
    const int MBb = Mc / 128;
    aquant_kernel<<<Mc, 256, 0, stream>>>(x + (size_t)c * D, D, qx, arow1);
    gemm_gateup<<<MBb * NBgu, 512, 0, stream>>>(qx, w1q, w2q, arow1, wsum,
                                                hbuf, hpart, H, D, MBb, NBgu);
    aquant_pre_kernel<<<Mc, 256, 0, stream>>>(hbuf, H, hpart, nslice, qh, arow2);
    gemm_down<<<MBb * NBdn, 512, 0, stream>>>(qh, w3q, arow2, wsum,
                                              out + (size_t)c * D, D, H, MBb, NBdn);
  }
}

// Round 8
// 483.222 us; speedup vs baseline: 1.0926x; 1.0926x over previous
//
#include <hip/hip_runtime.h>
#include <hip/hip_bf16.h>
#include <math.h>

#define EPSQ 1e-5f

typedef __attribute__((ext_vector_type(4))) int i32x4;

__device__ __forceinline__ void gload_lds16(const void* g, void* l) {
  __builtin_amdgcn_global_load_lds(
      (__attribute__((address_space(1))) void*)g,
      (__attribute__((address_space(3))) void*)l, 16, 0, 0);
}

__device__ __forceinline__ int clampi8(float v, float lo, float hi) {
  return (int)rintf(fminf(hi, fmaxf(lo, v)));
}

// ---------------- fused weight |w| sums: one dispatch, 3 weights ----------------
__global__ void wabs3_kernel(const float* __restrict__ w1, const float* __restrict__ w2,
                             const float* __restrict__ w3, int n4,
                             double* __restrict__ sums) {
  const float* w = (blockIdx.y == 0) ? w1 : (blockIdx.y == 1) ? w2 : w3;
  __shared__ double sm[256];
  const float4* w4 = (const float4*)w;
  double acc = 0.0;
  const int stride = gridDim.x * blockDim.x;
  for (int i = blockIdx.x * blockDim.x + threadIdx.x; i < n4; i += stride) {
    float4 v = w4[i];
    acc += (double)fabsf(v.x) + (double)fabsf(v.y) + (double)fabsf(v.z) + (double)fabsf(v.w);
  }
  sm[threadIdx.x] = acc;
  __syncthreads();
  for (int s = 128; s > 0; s >>= 1) {
    if ((int)threadIdx.x < s) sm[threadIdx.x] += sm[threadIdx.x + s];
    __syncthreads();
  }
  if (threadIdx.x == 0) atomicAdd(sums + blockIdx.y, sm[0]);
}

// ---------------- fused ternary weight quant: one dispatch, 3 weights ----------------
__global__ void wquant3_kernel(const float* __restrict__ w1, const float* __restrict__ w2,
                               const float* __restrict__ w3, int n4,
                               const double* __restrict__ sums, double inv_n,
                               unsigned int* __restrict__ q1, unsigned int* __restrict__ q2,
                               unsigned int* __restrict__ q3) {
  const int wsel = blockIdx.y;
  const float* w = (wsel == 0) ? w1 : (wsel == 1) ? w2 : w3;
  unsigned int* wq = (wsel == 0) ? q1 : (wsel == 1) ? q2 : q3;
  const float s = (float)fmax(sums[wsel] * inv_n, (double)EPSQ);
  const float scale = 1.0f / s;  // same fp32 division as the reference
  const int i = blockIdx.x * blockDim.x + threadIdx.x;
  if (i >= n4) return;
  float4 v = ((const float4*)w)[i];
  const int b0 = clampi8(rintf(v.x * scale), -1.f, 1.f);
  const int b1 = clampi8(rintf(v.y * scale), -1.f, 1.f);
  const int b2 = clampi8(rintf(v.z * scale), -1.f, 1.f);
  const int b3 = clampi8(rintf(v.w * scale), -1.f, 1.f);
  wq[i] = (unsigned int)((b0 & 0xff) | ((b1 & 0xff) << 8) |
                         ((b2 & 0xff) << 16) | ((b3 & 0xff) << 24));
}

// ---------------- per-token absmax int8 quant (2-pass, for x) ----------------
__global__ void aquant_kernel(const float* __restrict__ x, int K,
                              unsigned char* __restrict__ q, float* __restrict__ arow) {
  const int row = blockIdx.x;
  const int n4 = K >> 2;
  const float4* xr = (const float4*)(x + (size_t)row * K);
  float m = 0.f;
  for (int c = threadIdx.x; c < n4; c += blockDim.x) {
    float4 v = xr[c];
    m = fmaxf(m, fmaxf(fmaxf(fabsf(v.x), fabsf(v.y)), fmaxf(fabsf(v.z), fabsf(v.w))));
  }
  __shared__ float sm[256];
  sm[threadIdx.x] = m;
  __syncthreads();
  for (int s = 128; s > 0; s >>= 1) {
    if ((int)threadIdx.x < s) sm[threadIdx.x] = fmaxf(sm[threadIdx.x], sm[threadIdx.x + s]);
    __syncthreads();
  }
  const float mv = fmaxf(sm[0], EPSQ);
  const float scale = 127.0f / mv;   // same fp32 division as the reference
  if (threadIdx.x == 0) arow[row] = mv * (1.0f / 127.0f);
  unsigned int* qr = (unsigned int*)(q + (size_t)row * K);
  for (int c = threadIdx.x; c < n4; c += blockDim.x) {
    float4 v = xr[c];
    const int b0 = clampi8(v.x * scale, -128.f, 127.f);
    const int b1 = clampi8(v.y * scale, -128.f, 127.f);
    const int b2 = clampi8(v.z * scale, -128.f, 127.f);
    const int b3 = clampi8(v.w * scale, -128.f, 127.f);
    qr[c] = (unsigned int)((b0 & 0xff) | ((b1 & 0xff) << 8) |
                           ((b2 & 0xff) << 16) | ((b3 & 0xff) << 24));
  }
}

// ---------------- single-pass quant for h: reduce per-block partial maxima ----------------
__global__ void aquant_pre_kernel(const float* __restrict__ x, int K,
                                  const float* __restrict__ hpart, int nslice,
                                  unsigned char* __restrict__ q, float* __restrict__ arow) {
  const int row = blockIdx.x;
  __shared__ float sm[256];
  float m = 0.f;
  for (int t = threadIdx.x; t < nslice; t += blockDim.x)
    m = fmaxf(m, hpart[(size_t)row * nslice + t]);
  sm[threadIdx.x] = m;
  __syncthreads();
  for (int s = 128; s > 0; s >>= 1) {
    if ((int)threadIdx.x < s) sm[threadIdx.x] = fmaxf(sm[threadIdx.x], sm[threadIdx.x + s]);
    __syncthreads();
  }
  const float mv = fmaxf(sm[0], EPSQ);
  const float scale = 127.0f / mv;
  if (threadIdx.x == 0) arow[row] = mv * (1.0f / 127.0f);
  const int n4 = K >> 2;
  const float4* xr = (const float4*)(x + (size_t)row * K);
  unsigned int* qr = (unsigned int*)(q + (size_t)row * K);
  for (int c = threadIdx.x; c < n4; c += blockDim.x) {
    float4 v = xr[c];
    const int b0 = clampi8(v.x * scale, -128.f, 127.f);
    const int b1 = clampi8(v.y * scale, -128.f, 127.f);
    const int b2 = clampi8(v.z * scale, -128.f, 127.f);
    const int b3 = clampi8(v.w * scale, -128.f, 127.f);
    qr[c] = (unsigned int)((b0 & 0xff) | ((b1 & 0xff) << 8) |
                           ((b2 & 0xff) << 16) | ((b3 & 0xff) << 24));
  }
}

// =================================================================================
// Pipelined i8 GEMMs: tile 256(M)x128(N), BK=64, 8 waves (4Mx2N, 64x64 each),
// triple-buffered LDS slots, counted vmcnt (never 0 in loop), raw s_barrier,
// XOR-swizzled LDS (both sides: pre-swizzled global src + swizzled ds_read).
// Measured-best geometry (r4: 120.2 us/chunk gateup); epilogue partial-max is
// plain stores (r7: ~0 cost) instead of atomicMax (r5: +14 us).
// =================================================================================
#define BKP 64

#define PIPE_BARRIER(N)                                         \
  asm volatile("s_waitcnt vmcnt(" #N ")" ::: "memory");         \
  __builtin_amdgcn_s_barrier();                                 \
  asm volatile("" ::: "memory");

// ---------------- fused gate/up GEMM (int8, pipelined) ----------------
#define GU_SLOT 32768   // A 16KB + B1 8KB + B2 8KB

__launch_bounds__(512, 2)
__global__ void gemm_gateup(const unsigned char* __restrict__ Aq,   // [Mc][K] i8
                            const unsigned char* __restrict__ W1q,  // [N][K] i8 ternary
                            const unsigned char* __restrict__ W2q,  // [N][K]
                            const float* __restrict__ arow,         // [Mc] = rowmax/127
                            const double* __restrict__ wsum,
                            float* __restrict__ Hbuf,               // [Mc][N] fp32
                            float* __restrict__ hpart,              // [Mc][2*NBb] partial |h| max
                            const int N, const int K,
                            const int MBb, const int NBb) {
  __shared__ char lds[3 * GU_SLOT];   // 96 KiB

  const int tid = threadIdx.x;
  const int lane = tid & 63;
  const int wid = tid >> 6;          // 8 waves
  const int wm = wid >> 1;           // 0..3 (M)
  const int wn = wid & 1;            // 0..1 (N)

  // T1: XCD-aware block swizzle (bijective when total % 8 == 0)
  const int total = MBb * NBb;
  int swz = blockIdx.x;
  if ((total & 7) == 0) swz = (swz & 7) * (total >> 3) + (swz >> 3);
  const int nb = swz % NBb;          // nb fast: neighbors share the A panel
  const int mb = swz / NBb;
  const int m0 = mb * 256;
  const int n0 = nb * 128;

  const unsigned char* Ab  = Aq  + (size_t)m0 * K;
  const unsigned char* B1b = W1q + (size_t)n0 * K;
  const unsigned char* B2b = W2q + (size_t)n0 * K;

  // stage one K-tile into slot s: A 2 issues + B1 1 + B2 1 per wave (vmcnt +4)
  auto stage = [&](int kt, int s) {
    const int k0 = kt * BKP;
    char* base = lds + s * GU_SLOT;
#pragma unroll
    for (int is = 0; is < 2; ++is) {
      const int p = is * 8192 + wid * 1024 + lane * 16;   // phys byte in A region
      const int r = p >> 6;
      const int c = ((p >> 4) & 3) ^ ((r >> 1) & 3);      // inverse-swizzled source
      gload_lds16(Ab + (size_t)r * K + k0 + c * 16, base + is * 8192 + wid * 1024);
    }
    {
      const int p = wid * 1024 + lane * 16;
      const int r = p >> 6;
      const int c = ((p >> 4) & 3) ^ ((r >> 1) & 3);
      const size_t go = (size_t)r * K + k0 + c * 16;
      gload_lds16(B1b + go, base + 16384 + wid * 1024);
      gload_lds16(B2b + go, base + 24576 + wid * 1024);
    }
  };

  // precomputed swizzled read offsets (K-invariant)
  const int c16 = lane >> 4;
  int offA[4], offB1[4], offB2[4];
#pragma unroll
  for (int i = 0; i < 4; ++i) {
    const int row = wm * 64 + i * 16 + (lane & 15);
    offA[i] = row * 64 + ((c16 ^ ((row >> 1) & 3)) << 4);
  }
#pragma unroll
  for (int j = 0; j < 4; ++j) {
    const int n = wn * 64 + j * 16 + (lane & 15);
    const int o = n * 64 + ((c16 ^ ((n >> 1) & 3)) << 4);
    offB1[j] = 16384 + o;
    offB2[j] = 24576 + o;
  }

  i32x4 acc1[4][4] = {};
  i32x4 acc2[4][4] = {};

  const int NT = K / BKP;
  stage(0, 0);
  stage(1, 1);
  PIPE_BARRIER(4)                    // tile 0 landed; tile 1 (4 issues) in flight

  int s = 0, s2 = 2;
  for (int t = 0; t < NT; ++t) {
    if (t + 2 < NT) stage(t + 2, s2);   // issue-early; slot of t-1 (read-complete)
    const char* sb = lds + s * GU_SLOT;
    i32x4 af[4], b1f[4], b2f[4];
#pragma unroll
    for (int i = 0; i < 4; ++i) af[i] = *(const i32x4*)(sb + offA[i]);
#pragma unroll
    for (int j = 0; j < 4; ++j) {
      b1f[j] = *(const i32x4*)(sb + offB1[j]);
      b2f[j] = *(const i32x4*)(sb + offB2[j]);
    }
    __builtin_amdgcn_s_setprio(1);
#pragma unroll
    for (int j = 0; j < 4; ++j)
#pragma unroll
      for (int i = 0; i < 4; ++i) {
        acc1[i][j] = __builtin_amdgcn_mfma_i32_16x16x64_i8(af[i], b1f[j], acc1[i][j], 0, 0, 0);
        acc2[i][j] = __builtin_amdgcn_mfma_i32_16x16x64_i8(af[i], b2f[j], acc2[i][j], 0, 0, 0);
      }
    __builtin_amdgcn_s_setprio(0);
    if (t + 2 < NT) {
      PIPE_BARRIER(4)                // t+1 landed; t+2 stays in flight
    } else if (t + 1 < NT) {
      PIPE_BARRIER(0)                // tail: drain last tile
    }
    s = (s == 2) ? 0 : s + 1;
    s2 = (s2 == 2) ? 0 : s2 + 1;
  }

  // epilogue: dequant + silu(gate)*up, write fp32 H + per-(block,wn) row |h| max
  const double inv_n = 1.0 / 11534336.0;
  const float sw1 = (float)fmax(wsum[0] * inv_n, (double)EPSQ);
  const float sw2 = (float)fmax(wsum[1] * inv_n, (double)EPSQ);
  const int nslice = NBb * 2;
  const int slice = nb * 2 + wn;
#pragma unroll
  for (int i = 0; i < 4; ++i) {
    const int rb = m0 + wm * 64 + i * 16 + (lane >> 4) * 4;
#pragma unroll
    for (int qe = 0; qe < 4; ++qe) {
      const int grow = rb + qe;
      const float a = arow[grow];
      const float f1 = a * sw1;
      const float f2 = a * sw2;
      float* hr = Hbuf + (size_t)grow * N + n0 + wn * 64 + (lane & 15);
      float lmax = 0.f;
#pragma unroll
      for (int j = 0; j < 4; ++j) {
        const float y1 = (float)acc1[i][j][qe] * f1;
        const float y2 = (float)acc2[i][j][qe] * f2;
        const float h = (y1 / (1.0f + expf(-y1))) * y2;   // silu(y1)*y2
        hr[j * 16] = h;
        lmax = fmaxf(lmax, fabsf(h));
      }
      // reduce across the 16 lanes sharing this row (same lane>>4)
#pragma unroll
      for (int mk = 8; mk >= 1; mk >>= 1)
        lmax = fmaxf(lmax, __shfl_xor(lmax, mk, 64));
      if ((lane & 15) == 0)
        hpart[(size_t)grow * nslice + slice] = lmax;   // plain store, no atomics
    }
  }
}

// ---------------- down GEMM (int8, pipelined): Out = Q2 * W3^T ----------------
#define DN_SLOT 24576   // A 16KB + B 8KB

__launch_bounds__(512, 2)
__global__ void gemm_down(const unsigned char* __restrict__ Aq,   // [Mc][K] i8
                          const unsigned char* __restrict__ Wq,   // [N][K] i8 ternary
                          const float* __restrict__ arow,
                          const double* __restrict__ wsum,
                          float* __restrict__ Out,                // [Mc][N] fp32
                          const int N, const int K,
                          const int MBb, const int NBb) {
  __shared__ char lds[3 * DN_SLOT];   // 72 KiB

  const int tid = threadIdx.x;
  const int lane = tid & 63;
  const int wid = tid >> 6;
  const int wm = wid >> 1;
  const int wn = wid & 1;

  const int total = MBb * NBb;
  int swz = blockIdx.x;
  if ((total & 7) == 0) swz = (swz & 7) * (total >> 3) + (swz >> 3);
  const int nb = swz % NBb;
  const int mb = swz / NBb;
  const int m0 = mb * 256;
  const int n0 = nb * 128;

  const unsigned char* Ab = Aq + (size_t)m0 * K;
  const unsigned char* Bb = Wq + (size_t)n0 * K;

  auto stage = [&](int kt, int s) {
    const int k0 = kt * BKP;
    char* base = lds + s * DN_SLOT;
#pragma unroll
    for (int is = 0; is < 2; ++is) {
      const int p = is * 8192 + wid * 1024 + lane * 16;
      const int r = p >> 6;
      const int c = ((p >> 4) & 3) ^ ((r >> 1) & 3);
      gload_lds16(Ab + (size_t)r * K + k0 + c * 16, base + is * 8192 + wid * 1024);
    }
    {
      const int p = wid * 1024 + lane * 16;
      const int r = p >> 6;
      const int c = ((p >> 4) & 3) ^ ((r >> 1) & 3);
      gload_lds16(Bb + (size_t)r * K + k0 + c * 16, base + 16384 + wid * 1024);
    }
  };

  const int c16 = lane >> 4;
  int offA[4], offB[4];
#pragma unroll
  for (int i = 0; i < 4; ++i) {
    const int row = wm * 64 + i * 16 + (lane & 15);
    offA[i] = row * 64 + ((c16 ^ ((row >> 1) & 3)) << 4);
  }
#pragma unroll
  for (int j = 0; j < 4; ++j) {
    const int n = wn * 64 + j * 16 + (lane & 15);
    offB[j] = 16384 + n * 64 + ((c16 ^ ((n >> 1) & 3)) << 4);
  }

  i32x4 acc[4][4] = {};

  const int NT = K / BKP;
  stage(0, 0);
  stage(1, 1);
  PIPE_BARRIER(3)                    // 6 issued; tile 0 (3) landed

  int s = 0, s2 = 2;
  for (int t = 0; t < NT; ++t) {
    if (t + 2 < NT) stage(t + 2, s2);
    const char* sb = lds + s * DN_SLOT;
    i32x4 af[4], bf[4];
#pragma unroll
    for (int i = 0; i < 4; ++i) af[i] = *(const i32x4*)(sb + offA[i]);
#pragma unroll
    for (int j = 0; j < 4; ++j) bf[j] = *(const i32x4*)(sb + offB[j]);
    __builtin_amdgcn_s_setprio(1);
#pragma unroll
    for (int j = 0; j < 4; ++j)
#pragma unroll
      for (int i = 0; i < 4; ++i)
        acc[i][j] = __builtin_amdgcn_mfma_i32_16x16x64_i8(af[i], bf[j], acc[i][j], 0, 0, 0);
    __builtin_amdgcn_s_setprio(0);
    if (t + 2 < NT) {
      PIPE_BARRIER(3)
    } else if (t + 1 < NT) {
      PIPE_BARRIER(0)
    }
    s = (s == 2) ? 0 : s + 1;
    s2 = (s2 == 2) ? 0 : s2 + 1;
  }

  const double inv_n = 1.0 / 11534336.0;
  const float sw3 = (float)fmax(wsum[2] * inv_n, (double)EPSQ);
#pragma unroll
  for (int i = 0; i < 4; ++i) {
    const int rb = m0 + wm * 64 + i * 16 + (lane >> 4) * 4;
#pragma unroll
    for (int qe = 0; qe < 4; ++qe) {
      const int grow = rb + qe;
      const float f = arow[grow] * sw3;
      float* orow = Out + (size_t)grow * N + n0 + wn * 64 + (lane & 15);
#pragma unroll
      for (int j = 0; j < 4; ++j) {
        orow[j * 16] = (float)acc[i][j][qe] * f;
      }
    }
  }
}

extern "C" void kernel_launch(void* const* d_in, const int* in_sizes, int n_in,
                              void* d_out, int out_size, void* d_ws, size_t ws_size,
                              hipStream_t stream) {
  (void)n_in; (void)out_size;
  const float* x  = (const float*)d_in[0];
  const float* w1 = (const float*)d_in[1];
  const float* w2 = (const float*)d_in[2];
  const float* w3 = (const float*)d_in[3];
  float* out = (float*)d_out;

  const int D = 2048, H = 5632;
  const int M = in_sizes[0] / D;             // 8192
  const long long NW = (long long)H * D;     // 11534336
  const int NBgu = H / 128;                  // 44
  const int NBdn = D / 128;                  // 16
  const int nslice = NBgu * 2;               // 88

  auto al = [](size_t v) { return (v + 255) & ~(size_t)255; };

  // fixed region: wsum + int8 quantized weights (34.6 MB)
  size_t off = 0;
  const size_t o_wsum = off; off += al(3 * sizeof(double));
  const size_t o_w1q  = off; off += al((size_t)NW);
  const size_t o_w2q  = off; off += al((size_t)NW);
  const size_t o_w3q  = off; off += al((size_t)NW);
  const size_t fixed = off;

  // adaptive chunk size: largest Mc (multiple of 256, power-of-2 fraction of M)
  int Mc = 256;
  for (int cand = M; cand >= 256; cand >>= 1) {
    size_t need = fixed
                + al((size_t)cand * 4)            // arow1
                + al((size_t)cand * 4)            // arow2
                + al((size_t)cand * nslice * 4)   // hpart
                + al((size_t)cand * D)            // qx i8
                + al((size_t)cand * H * 4)        // hbuf fp32
                + al((size_t)cand * H);           // qh i8
    if (need <= ws_size) { Mc = cand; break; }
  }

  size_t coff = fixed;
  const size_t o_arow1 = coff; coff += al((size_t)Mc * 4);
  const size_t o_arow2 = coff; coff += al((size_t)Mc * 4);
  const size_t o_hpart = coff; coff += al((size_t)Mc * nslice * 4);
  const size_t o_qx    = coff; coff += al((size_t)Mc * D);
  const size_t o_hbuf  = coff; coff += al((size_t)Mc * H * 4);
  const size_t o_qh    = coff; coff += al((size_t)Mc * H);

  char* ws = (char*)d_ws;
  double* wsum        = (double*)(ws + o_wsum);
  unsigned char* w1q  = (unsigned char*)(ws + o_w1q);
  unsigned char* w2q  = (unsigned char*)(ws + o_w2q);
  unsigned char* w3q  = (unsigned char*)(ws + o_w3q);
  float* arow1        = (float*)(ws + o_arow1);
  float* arow2        = (float*)(ws + o_arow2);
  float* hpart        = (float*)(ws + o_hpart);
  unsigned char* qx   = (unsigned char*)(ws + o_qx);
  float* hbuf         = (float*)(ws + o_hbuf);
  unsigned char* qh   = (unsigned char*)(ws + o_qh);

  hipMemsetAsync(wsum, 0, 3 * sizeof(double), stream);

  const int n4w = (int)(NW / 4);                 // 2883584
  wabs3_kernel<<<dim3(1024, 3), 256, 0, stream>>>(w1, w2, w3, n4w, wsum);

  const double inv_n = 1.0 / (double)NW;
  wquant3_kernel<<<dim3(n4w / 256, 3), 256, 0, stream>>>(
      w1, w2, w3, n4w, wsum, inv_n,
      (unsigned int*)w1q, (unsigned int*)w2q, (unsigned int*)w3q);

  for (int c = 0; c < M; c += Mc) {
    const int MBb = Mc / 256;
    aquant_kernel<<<Mc, 256, 0, stream>>>(x + (size_t)c * D, D, qx, arow1);
    gemm_gateup<<<MBb * NBgu, 512, 0, stream>>>(qx, w1q, w2q, arow1, wsum,
                                                hbuf, hpart, H, D, MBb, NBgu);
    aquant_pre_kernel<<<Mc, 256, 0, stream>>>(hbuf, H, hpart, nslice, qh, arow2);
    gemm_down<<<MBb * NBdn, 512, 0, stream>>>(qh, w3q, arow2, wsum,
                                              out + (size_t)c * D, D, H, MBb, NBdn);
  }
}